// Round 1
// 1085.576 us; speedup vs baseline: 1.2178x; 1.2178x over previous
//
#include <hip/hip_runtime.h>
#include <hip/hip_bf16.h>

#define VOCAB 32000
#define RANK  32
#define BEAM  64
#define BB    8
#define SS    512
#define KSEL  63   // beam slots besides the forced target

#define LOG2E 1.4426950408889634f
#define LN2   0.6931471805599453f

typedef _Float16 half2v __attribute__((ext_vector_type(2)));

__device__ __forceinline__ unsigned sortkey(float f) {
    unsigned u = __float_as_uint(f);
    return u ^ (((unsigned)((int)u >> 31)) | 0x80000000u);
}
__device__ __forceinline__ float keyfloat(unsigned k) {
    unsigned u = (k & 0x80000000u) ? (k ^ 0x80000000u) : ~k;
    return __uint_as_float(u);
}
__device__ __forceinline__ float wavesum(float x) {
    #pragma unroll
    for (int off = 32; off > 0; off >>= 1) x += __shfl_xor(x, off, 64);
    return x;
}
__device__ __forceinline__ float rl(float x, int lane) {
    return __builtin_bit_cast(float, __builtin_amdgcn_readlane(__builtin_bit_cast(int, x), lane));
}
__device__ __forceinline__ float fdot2f(float a, float b, float c) {
#if __has_builtin(__builtin_amdgcn_fdot2)
    return __builtin_amdgcn_fdot2(__builtin_bit_cast(half2v, a),
                                  __builtin_bit_cast(half2v, b), c, false);
#else
    half2v ha = __builtin_bit_cast(half2v, a), hb = __builtin_bit_cast(half2v, b);
    return fmaf((float)ha.x, (float)hb.x, fmaf((float)ha.y, (float)hb.y, c));
#endif
}

// ---------------- numerator ----------------
__global__ __launch_bounds__(256) void num_kernel(
    const float* __restrict__ emissions, const int* __restrict__ targets,
    const float* __restrict__ E1, const float* __restrict__ E2,
    float* __restrict__ numer)
{
    int b = blockIdx.x, tid = threadIdx.x;
    float acc = 0.f;
    for (int s = tid; s < SS; s += 256) {
        int t = targets[b * SS + s];
        acc += emissions[((size_t)(b * SS + s)) * VOCAB + t];
        if (s > 0) {
            int tp = targets[b * SS + s - 1];
            const float* r1 = E1 + (size_t)tp * RANK;
            const float* r2 = E2 + (size_t)t * RANK;
            float d = 0.f;
            #pragma unroll
            for (int r = 0; r < RANK; ++r) d = fmaf(r1[r], r2[r], d);
            acc += d;
        }
    }
    __shared__ float red[256];
    red[tid] = acc;
    __syncthreads();
    for (int w = 128; w >= 1; w >>= 1) {
        if (tid < w) red[tid] += red[tid + w];
        __syncthreads();
    }
    if (tid == 0) numer[b] = red[0];
}

// ---------------- parallel threshold selection from an LDS histogram ----------
// Find largest bin b such that (count strictly above b) < need <= (count >= b).
// result[0] = b, result[1] = need - (count strictly above b).
// All 256 threads participate; contains barriers; result valid on return.
template<int NB>
__device__ __forceinline__ void select_from_hist(
    const unsigned* hist, unsigned need,
    unsigned* wsum /*[4] LDS*/, unsigned* result /*[2] LDS*/)
{
    constexpr int BPT = NB / 256;
    const int tid  = threadIdx.x;
    const int lane = tid & 63, wid = tid >> 6;
    const int base = tid * BPT;

    unsigned local = 0;
    #pragma unroll
    for (int i = 0; i < BPT; ++i) local += hist[base + i];

    // inclusive suffix-sum across the wave (lane l gets sum over lanes >= l)
    unsigned x = local;
    #pragma unroll
    for (int off = 1; off < 64; off <<= 1) {
        unsigned v = __shfl_down(x, off, 64);
        x += (lane + off < 64) ? v : 0u;
    }
    if (lane == 0) wsum[wid] = x;   // wave total
    __syncthreads();

    unsigned add = 0;
    #pragma unroll
    for (int w = 0; w < 4; ++w) add += (w > wid) ? wsum[w] : 0u;

    const unsigned S_incl = x + add;       // count in bins >= base
    const unsigned S_excl = S_incl - local; // count in bins >= base+BPT
    if (S_excl < need && S_incl >= need) {  // exactly one thread
        unsigned cum = S_excl;
        #pragma unroll
        for (int i = BPT - 1; i >= 0; --i) {
            unsigned h = hist[base + i];
            if (cum + h >= need) { result[0] = (unsigned)(base + i); result[1] = need - cum; break; }
            cum += h;
        }
    }
    __syncthreads();
}

// ---------------- exact top-64 per (b,s) ----------------
#define CCAP 2048
__global__ __launch_bounds__(256) void topk_kernel(
    const float* __restrict__ emissions, const int* __restrict__ targets,
    int* __restrict__ beam_tgt, float* __restrict__ beam_em)
{
    __shared__ unsigned hist[4096];
    __shared__ unsigned s_ws[4];
    __shared__ unsigned s_sel[2];
    __shared__ unsigned s_cnt[2];
    __shared__ unsigned s_ccount;
    __shared__ unsigned ckey[CCAP];
    __shared__ unsigned cidx[CCAP];

    const int bs  = blockIdx.x;
    const int tid = threadIdx.x;
    const float* row = emissions + (size_t)bs * VOCAB;
    const int tgt = targets[bs];

    for (int i = tid; i < 4096; i += 256) hist[i] = 0;
    if (tid == 0) { s_ccount = 0; s_cnt[0] = 1; s_cnt[1] = 0; }
    __syncthreads();

    // pass 1: 12-bit histogram of sort keys
    for (int i4 = tid; i4 < VOCAB / 4; i4 += 256) {
        float4 v = ((const float4*)row)[i4];
        int base = i4 * 4;
        #pragma unroll
        for (int j = 0; j < 4; ++j) {
            float f = (j == 0) ? v.x : (j == 1) ? v.y : (j == 2) ? v.z : v.w;
            int idx = base + j;
            if (idx != tgt) atomicAdd(&hist[sortkey(f) >> 20], 1u);
        }
    }
    __syncthreads();

    // level-1 select (parallel; replaces serial tid0 scans)
    select_from_hist<4096>(hist, KSEL, s_ws, s_sel);
    const unsigned b1 = s_sel[0], need1 = s_sel[1];

    int*   bt = beam_tgt + (size_t)bs * BEAM;
    float* be = beam_em  + (size_t)bs * BEAM;

    // pass 2: emit certain winners, capture threshold-bin candidates
    for (int i4 = tid; i4 < VOCAB / 4; i4 += 256) {
        float4 v = ((const float4*)row)[i4];
        int base = i4 * 4;
        #pragma unroll
        for (int j = 0; j < 4; ++j) {
            float f = (j == 0) ? v.x : (j == 1) ? v.y : (j == 2) ? v.z : v.w;
            int idx = base + j;
            if (idx == tgt) continue;
            unsigned key = sortkey(f);
            unsigned bin = key >> 20;
            if (bin > b1) {
                unsigned p = atomicAdd(&s_cnt[0], 1u);
                if (p < BEAM) { bt[p] = idx; be[p] = f; }
            } else if (bin == b1) {
                unsigned c = atomicAdd(&s_ccount, 1u);
                if (c < CCAP) { ckey[c] = key; cidx[c] = idx; }
            }
        }
    }
    __syncthreads();
    const unsigned C = min(s_ccount, (unsigned)CCAP);

    // level-2: 10-bit histogram (key bits 19:10) over candidates
    for (int i = tid; i < 1024; i += 256) hist[i] = 0;
    __syncthreads();
    for (int i = tid; i < (int)C; i += 256) atomicAdd(&hist[(ckey[i] >> 10) & 1023], 1u);
    __syncthreads();
    select_from_hist<1024>(hist, need1, s_ws, s_sel);
    const unsigned b2 = s_sel[0], need2 = s_sel[1];

    // level-3: 10-bit histogram (key bits 9:0) within bin b2
    for (int i = tid; i < 1024; i += 256) hist[i] = 0;
    __syncthreads();
    for (int i = tid; i < (int)C; i += 256) {
        unsigned k = ckey[i];
        if (((k >> 10) & 1023) == b2) atomicAdd(&hist[k & 1023], 1u);
    }
    __syncthreads();
    select_from_hist<1024>(hist, need2, s_ws, s_sel);
    const unsigned Kthr = (b1 << 20) | (b2 << 10) | s_sel[0];
    const unsigned tieNeed = s_sel[1];

    for (int i = tid; i < (int)C; i += 256) {
        unsigned k = ckey[i];
        if (k > Kthr) {
            unsigned p = atomicAdd(&s_cnt[0], 1u);
            if (p < BEAM) { bt[p] = cidx[i]; be[p] = keyfloat(k); }
        } else if (k == Kthr) {
            unsigned t = atomicAdd(&s_cnt[1], 1u);
            if (t < tieNeed) {
                unsigned p = atomicAdd(&s_cnt[0], 1u);
                if (p < BEAM) { bt[p] = cidx[i]; be[p] = keyfloat(k); }
            }
        }
    }
    if (tid == 0) { bt[0] = tgt; be[0] = row[tgt]; }
}

// ---------------- T = exp(trans) per step, f16, layout [b][t1][l][k] ----------------
__global__ __launch_bounds__(256) void trans_kernel(
    const float* __restrict__ E1, const float* __restrict__ E2,
    const int* __restrict__ beam_tgt, unsigned short* __restrict__ Tbuf)
{
    int blk = blockIdx.x;
    int b = blk / (SS - 1), t1 = blk % (SS - 1);
    __shared__ float e1r[64][33];
    __shared__ float e2r[64][33];
    const int* btk = beam_tgt + ((size_t)(b * SS + t1)) * BEAM;
    const int* btl = btk + BEAM;
    int tid = threadIdx.x;
    for (int j = tid; j < 64 * RANK; j += 256) {
        int r = j & 31, q = j >> 5;
        e1r[q][r] = E1[(size_t)btk[q] * RANK + r];
        e2r[q][r] = E2[(size_t)btl[q] * RANK + r];
    }
    __syncthreads();
    int l = tid & 63, g = tid >> 6;
    unsigned short* out = Tbuf + ((size_t)(b * (SS - 1) + t1)) * (BEAM * BEAM);
    for (int kk = 0; kk < 16; ++kk) {
        int k = g * 16 + kk;
        float d = 0.f;
        #pragma unroll
        for (int r = 0; r < RANK; ++r) d = fmaf(e1r[k][r], e2r[l][r], d);
        float T = __expf(d);
        _Float16 h = (_Float16)T;
        out[(size_t)l * BEAM + k] = __builtin_bit_cast(unsigned short, h);
    }
}

// ---------------- sequential beam recursion, 1 wave per batch ----------------
// T rows (per l): 64 f16 = 32 dwords = 8 uint4. 4-deep register prefetch.
__global__ __launch_bounds__(64) void recur_kernel(
    const unsigned short* __restrict__ Tbuf, const float* __restrict__ beam_em,
    float* __restrict__ denom)
{
    int b = blockIdx.x, l = threadIdx.x;
    const float* bem = beam_em + (size_t)b * SS * BEAM;
    float sc = bem[l] * LOG2E;
    float M = __builtin_bit_cast(float, __builtin_amdgcn_readfirstlane(__builtin_bit_cast(int, sc)));
    float r = sc - M;

    const uint4* Trow = (const uint4*)(Tbuf + (size_t)b * (SS - 1) * (BEAM * BEAM)) + (size_t)l * 8;

    uint4 b0[8], b1[8], b2[8], b3[8];
    float bm0, bm1, bm2, bm3;

#define LOADT(BUF, STP) do { \
    const uint4* _p = Trow + (size_t)(STP) * 512; \
    _Pragma("unroll") \
    for (int i = 0; i < 8; ++i) BUF[i] = _p[i]; \
} while (0)

    LOADT(b0, 0); LOADT(b1, 1); LOADT(b2, 2); LOADT(b3, 3);
    bm0 = bem[1 * BEAM + l]; bm1 = bem[2 * BEAM + l];
    bm2 = bem[3 * BEAM + l]; bm3 = bem[4 * BEAM + l];

#define STEP(BUF, BEMV) do { \
    float e = exp2f(r); \
    float eo = __shfl_down(e, 1, 64); \
    half2v ep; ep.x = (_Float16)e; ep.y = (_Float16)eo; \
    float epf = __builtin_bit_cast(float, ep); \
    float a0 = 0.f, a1 = 0.f, a2 = 0.f, a3 = 0.f; \
    _Pragma("unroll") \
    for (int i = 0; i < 8; ++i) { \
        uint4 v = BUF[i]; \
        a0 = fdot2f(rl(epf, 8 * i + 0), __builtin_bit_cast(float, v.x), a0); \
        a1 = fdot2f(rl(epf, 8 * i + 2), __builtin_bit_cast(float, v.y), a1); \
        a2 = fdot2f(rl(epf, 8 * i + 4), __builtin_bit_cast(float, v.z), a2); \
        a3 = fdot2f(rl(epf, 8 * i + 6), __builtin_bit_cast(float, v.w), a3); \
    } \
    float u = __log2f((a0 + a1) + (a2 + a3)) + (BEMV) * LOG2E; \
    float d = __builtin_bit_cast(float, __builtin_amdgcn_readfirstlane(__builtin_bit_cast(int, u))); \
    r = u - d; M += d; \
} while (0)

    for (int t = 0; t <= 504; t += 4) {
        STEP(b0, bm0);
        if (t + 4 < 511) { LOADT(b0, t + 4); bm0 = bem[(size_t)(t + 5) * BEAM + l]; }
        STEP(b1, bm1);
        if (t + 5 < 511) { LOADT(b1, t + 5); bm1 = bem[(size_t)(t + 6) * BEAM + l]; }
        STEP(b2, bm2);
        if (t + 6 < 511) { LOADT(b2, t + 6); bm2 = bem[(size_t)(t + 7) * BEAM + l]; }
        STEP(b3, bm3);
        if (t + 7 < 511) { LOADT(b3, t + 7); bm3 = bem[(size_t)(t + 8) * BEAM + l]; }
    }
    // steps 508, 509, 510
    STEP(b0, bm0);
    STEP(b1, bm1);
    STEP(b2, bm2);

    float e = exp2f(r);
    float s = wavesum(e);
    if (l == 0) denom[b] = (__log2f(s) + M) * LN2;
#undef STEP
#undef LOADT
}

// ---------------- finalize ----------------
__global__ __launch_bounds__(64) void fin_kernel(
    const float* __restrict__ numer, const float* __restrict__ denom,
    float* __restrict__ out)
{
    int tid = threadIdx.x;
    float llh = 0.f;
    if (tid < BB) {
        llh = numer[tid] - denom[tid];
        out[1 + tid] = llh;
    }
    float s = llh;
    #pragma unroll
    for (int off = 4; off > 0; off >>= 1) s += __shfl_xor(s, off, 64);
    if (tid == 0) out[0] = s;
}

extern "C" void kernel_launch(void* const* d_in, const int* in_sizes, int n_in,
                              void* d_out, int out_size, void* d_ws, size_t ws_size,
                              hipStream_t stream) {
    const float* emissions = (const float*)d_in[0];
    const int*   targets   = (const int*)d_in[1];
    const float* E1        = (const float*)d_in[3];
    const float* E2        = (const float*)d_in[4];
    float* out = (float*)d_out;

    char* w = (char*)d_ws;
    float* numer = (float*)w;
    float* denom = numer + 64;
    int*   btgt  = (int*)(w + 512);
    float* bem   = (float*)(w + 512 + (1u << 20));
    unsigned short* Tbuf = (unsigned short*)(w + 512 + (2u << 20));

    num_kernel  <<<BB, 256, 0, stream>>>(emissions, targets, E1, E2, numer);
    topk_kernel <<<BB * SS, 256, 0, stream>>>(emissions, targets, btgt, bem);
    trans_kernel<<<BB * (SS - 1), 256, 0, stream>>>(E1, E2, btgt, Tbuf);
    recur_kernel<<<BB, 64, 0, stream>>>(Tbuf, bem, denom);
    fin_kernel  <<<1, 64, 0, stream>>>(numer, denom, out);
}

// Round 3
// 969.945 us; speedup vs baseline: 1.3630x; 1.1192x over previous
//
#include <hip/hip_runtime.h>
#include <hip/hip_bf16.h>

#define VOCAB 32000
#define RANK  32
#define BEAM  64
#define BB    8
#define SS    512
#define KSEL  63   // beam slots besides the forced target

#define LOG2E 1.4426950408889634f
#define LN2   0.6931471805599453f

typedef _Float16 half2v __attribute__((ext_vector_type(2)));
typedef _Float16 half8  __attribute__((ext_vector_type(8)));
typedef float    f32x4  __attribute__((ext_vector_type(4)));

__device__ __forceinline__ unsigned sortkey(float f) {
    unsigned u = __float_as_uint(f);
    return u ^ (((unsigned)((int)u >> 31)) | 0x80000000u);
}
__device__ __forceinline__ float keyfloat(unsigned k) {
    unsigned u = (k & 0x80000000u) ? (k ^ 0x80000000u) : ~k;
    return __uint_as_float(u);
}
__device__ __forceinline__ float wavesum(float x) {
    #pragma unroll
    for (int off = 32; off > 0; off >>= 1) x += __shfl_xor(x, off, 64);
    return x;
}
__device__ __forceinline__ float rl(float x, int lane) {
    return __builtin_bit_cast(float, __builtin_amdgcn_readlane(__builtin_bit_cast(int, x), lane));
}
__device__ __forceinline__ float rfl(float x) {
    return __builtin_bit_cast(float, __builtin_amdgcn_readfirstlane(__builtin_bit_cast(int, x)));
}
__device__ __forceinline__ float fdot2f(float a, float b, float c) {
#if __has_builtin(__builtin_amdgcn_fdot2)
    return __builtin_amdgcn_fdot2(__builtin_bit_cast(half2v, a),
                                  __builtin_bit_cast(half2v, b), c, false);
#else
    half2v ha = __builtin_bit_cast(half2v, a), hb = __builtin_bit_cast(half2v, b);
    return fmaf((float)ha.x, (float)hb.x, fmaf((float)ha.y, (float)hb.y, c));
#endif
}
// lane^1 neighbor exchange, 1 VALU op (quad_perm [1,0,3,2])
__device__ __forceinline__ float dpp_xor1(float x) {
#if __has_builtin(__builtin_amdgcn_mov_dpp)
    return __builtin_bit_cast(float,
        __builtin_amdgcn_mov_dpp(__builtin_bit_cast(int, x), 0xB1, 0xF, 0xF, true));
#else
    return __shfl_xor(x, 1, 64);
#endif
}

// ---------------- numerator ----------------
__global__ __launch_bounds__(256) void num_kernel(
    const float* __restrict__ emissions, const int* __restrict__ targets,
    const float* __restrict__ E1, const float* __restrict__ E2,
    float* __restrict__ numer)
{
    int b = blockIdx.x, tid = threadIdx.x;
    float acc = 0.f;
    for (int s = tid; s < SS; s += 256) {
        int t = targets[b * SS + s];
        acc += emissions[((size_t)(b * SS + s)) * VOCAB + t];
        if (s > 0) {
            int tp = targets[b * SS + s - 1];
            const float* r1 = E1 + (size_t)tp * RANK;
            const float* r2 = E2 + (size_t)t * RANK;
            float d = 0.f;
            #pragma unroll
            for (int r = 0; r < RANK; ++r) d = fmaf(r1[r], r2[r], d);
            acc += d;
        }
    }
    __shared__ float red[256];
    red[tid] = acc;
    __syncthreads();
    for (int w = 128; w >= 1; w >>= 1) {
        if (tid < w) red[tid] += red[tid + w];
        __syncthreads();
    }
    if (tid == 0) numer[b] = red[0];
}

// ---------------- parallel threshold selection from an LDS histogram ----------
template<int NB>
__device__ __forceinline__ void select_from_hist(
    const unsigned* hist, unsigned need,
    unsigned* wsum /*[4] LDS*/, unsigned* result /*[2] LDS*/)
{
    constexpr int BPT = NB / 256;
    const int tid  = threadIdx.x;
    const int lane = tid & 63, wid = tid >> 6;
    const int base = tid * BPT;

    unsigned local = 0;
    #pragma unroll
    for (int i = 0; i < BPT; ++i) local += hist[base + i];

    unsigned x = local;
    #pragma unroll
    for (int off = 1; off < 64; off <<= 1) {
        unsigned v = __shfl_down(x, off, 64);
        x += (lane + off < 64) ? v : 0u;
    }
    if (lane == 0) wsum[wid] = x;
    __syncthreads();

    unsigned add = 0;
    #pragma unroll
    for (int w = 0; w < 4; ++w) add += (w > wid) ? wsum[w] : 0u;

    const unsigned S_incl = x + add;
    const unsigned S_excl = S_incl - local;
    if (S_excl < need && S_incl >= need) {
        unsigned cum = S_excl;
        #pragma unroll
        for (int i = BPT - 1; i >= 0; --i) {
            unsigned h = hist[base + i];
            if (cum + h >= need) { result[0] = (unsigned)(base + i); result[1] = need - cum; break; }
            cum += h;
        }
    }
    __syncthreads();
}

// ---------------- exact top-64 per (b,s) ----------------
#define CCAP 2048
__global__ __launch_bounds__(256) void topk_kernel(
    const float* __restrict__ emissions, const int* __restrict__ targets,
    int* __restrict__ beam_tgt, float* __restrict__ beam_em)
{
    __shared__ unsigned hist[4096];
    __shared__ unsigned s_ws[4];
    __shared__ unsigned s_sel[2];
    __shared__ unsigned s_cnt[2];
    __shared__ unsigned s_ccount;
    __shared__ unsigned ckey[CCAP];
    __shared__ unsigned cidx[CCAP];

    const int bs  = blockIdx.x;
    const int tid = threadIdx.x;
    const float* row = emissions + (size_t)bs * VOCAB;
    const int tgt = targets[bs];

    for (int i = tid; i < 4096; i += 256) hist[i] = 0;
    if (tid == 0) { s_ccount = 0; s_cnt[0] = 1; s_cnt[1] = 0; }
    __syncthreads();

    for (int i4 = tid; i4 < VOCAB / 4; i4 += 256) {
        float4 v = ((const float4*)row)[i4];
        int base = i4 * 4;
        #pragma unroll
        for (int j = 0; j < 4; ++j) {
            float f = (j == 0) ? v.x : (j == 1) ? v.y : (j == 2) ? v.z : v.w;
            int idx = base + j;
            if (idx != tgt) atomicAdd(&hist[sortkey(f) >> 20], 1u);
        }
    }
    __syncthreads();

    select_from_hist<4096>(hist, KSEL, s_ws, s_sel);
    const unsigned b1 = s_sel[0], need1 = s_sel[1];

    int*   bt = beam_tgt + (size_t)bs * BEAM;
    float* be = beam_em  + (size_t)bs * BEAM;

    for (int i4 = tid; i4 < VOCAB / 4; i4 += 256) {
        float4 v = ((const float4*)row)[i4];
        int base = i4 * 4;
        #pragma unroll
        for (int j = 0; j < 4; ++j) {
            float f = (j == 0) ? v.x : (j == 1) ? v.y : (j == 2) ? v.z : v.w;
            int idx = base + j;
            if (idx == tgt) continue;
            unsigned key = sortkey(f);
            unsigned bin = key >> 20;
            if (bin > b1) {
                unsigned p = atomicAdd(&s_cnt[0], 1u);
                if (p < BEAM) { bt[p] = idx; be[p] = f; }
            } else if (bin == b1) {
                unsigned c = atomicAdd(&s_ccount, 1u);
                if (c < CCAP) { ckey[c] = key; cidx[c] = idx; }
            }
        }
    }
    __syncthreads();
    const unsigned C = min(s_ccount, (unsigned)CCAP);

    for (int i = tid; i < 1024; i += 256) hist[i] = 0;
    __syncthreads();
    for (int i = tid; i < (int)C; i += 256) atomicAdd(&hist[(ckey[i] >> 10) & 1023], 1u);
    __syncthreads();
    select_from_hist<1024>(hist, need1, s_ws, s_sel);
    const unsigned b2 = s_sel[0], need2 = s_sel[1];

    for (int i = tid; i < 1024; i += 256) hist[i] = 0;
    __syncthreads();
    for (int i = tid; i < (int)C; i += 256) {
        unsigned k = ckey[i];
        if (((k >> 10) & 1023) == b2) atomicAdd(&hist[k & 1023], 1u);
    }
    __syncthreads();
    select_from_hist<1024>(hist, need2, s_ws, s_sel);
    const unsigned Kthr = (b1 << 20) | (b2 << 10) | s_sel[0];
    const unsigned tieNeed = s_sel[1];

    for (int i = tid; i < (int)C; i += 256) {
        unsigned k = ckey[i];
        if (k > Kthr) {
            unsigned p = atomicAdd(&s_cnt[0], 1u);
            if (p < BEAM) { bt[p] = cidx[i]; be[p] = keyfloat(k); }
        } else if (k == Kthr) {
            unsigned t = atomicAdd(&s_cnt[1], 1u);
            if (t < tieNeed) {
                unsigned p = atomicAdd(&s_cnt[0], 1u);
                if (p < BEAM) { bt[p] = cidx[i]; be[p] = keyfloat(k); }
            }
        }
    }
    if (tid == 0) { bt[0] = tgt; be[0] = row[tgt]; }
}

// ---------------- T'' = exp(trans + em_next) per step via MFMA -----------------
// layout [b][t1][l][k], l = new-beam (rows), k = old-beam (cols), f16.
// D = A·B with A[l][r] = f16(E2[btl[l]][r]), B[r][k] = f16(E1[btk[k]][r]), K=RANK=32.
// mfma_f32_16x16x32_f16: A lane = row(l&15), k=(lane>>4)*8+j ; B lane = col, same k;
// D lane: col = lane&15, row = (lane>>4)*4 + reg  [m89-verified, dtype-independent].
__global__ __launch_bounds__(256) void trans_kernel(
    const float* __restrict__ E1, const float* __restrict__ E2,
    const int* __restrict__ beam_tgt, const float* __restrict__ beam_em,
    unsigned short* __restrict__ Tbuf)
{
    int blk = blockIdx.x;
    int b = blk / (SS - 1), t1 = blk % (SS - 1);
    const int* btk = beam_tgt + ((size_t)(b * SS + t1)) * BEAM;      // old beam (k)
    const int* btl = btk + BEAM;                                      // new beam (l)
    const float* em = beam_em + ((size_t)(b * SS + t1 + 1)) * BEAM;   // em of new beam

    const int tid  = threadIdx.x;
    const int w    = tid >> 6;         // wave id 0..3: rows w*16..w*16+15
    const int lane = tid & 63;
    const int hl   = lane & 15;
    const int kg   = lane >> 4;        // k-group: elements kg*8 .. kg*8+7

    // A fragment: e2 row (l = w*16 + hl), r = kg*8..+7
    const float* pa = E2 + (size_t)btl[w * 16 + hl] * RANK + kg * 8;
    half8 afrag;
    #pragma unroll
    for (int j = 0; j < 8; ++j) afrag[j] = (_Float16)pa[j];

    // B fragments: e1 rows (k = t*16 + hl)
    half8 bfrag[4];
    #pragma unroll
    for (int t = 0; t < 4; ++t) {
        const float* pb = E1 + (size_t)btk[t * 16 + hl] * RANK + kg * 8;
        #pragma unroll
        for (int j = 0; j < 8; ++j) bfrag[t][j] = (_Float16)pb[j];
    }

    // em for the 4 output rows this lane owns
    float emv[4];
    #pragma unroll
    for (int q = 0; q < 4; ++q) emv[q] = em[w * 16 + kg * 4 + q];

    unsigned short* out = Tbuf + ((size_t)(b * (SS - 1) + t1)) * (BEAM * BEAM);
    #pragma unroll
    for (int t = 0; t < 4; ++t) {
        f32x4 acc = {0.f, 0.f, 0.f, 0.f};
        acc = __builtin_amdgcn_mfma_f32_16x16x32_f16(afrag, bfrag[t], acc, 0, 0, 0);
        #pragma unroll
        for (int q = 0; q < 4; ++q) {
            int lg  = w * 16 + kg * 4 + q;   // output row (new beam)
            int kgc = t * 16 + hl;           // output col (old beam)
            float T = exp2f((acc[q] + emv[q]) * LOG2E);
            _Float16 h = (_Float16)T;
            out[(size_t)lg * BEAM + kgc] = __builtin_bit_cast(unsigned short, h);
        }
    }
}

// ---------------- sequential beam recursion, 1 wave per batch ----------------
// Linear form: v' = T''^T v (T'' has exp(em) fused); renorm by v0 each step.
// Per-step chain: cvt_pk -> readlane -> fdot2(4-deep x8) -> add tree -> rfl -> rcp -> mul
__global__ __launch_bounds__(64) void recur_kernel(
    const unsigned short* __restrict__ Tbuf, const float* __restrict__ beam_em,
    float* __restrict__ denom)
{
    int b = blockIdx.x, l = threadIdx.x;
    const float* bem = beam_em + (size_t)b * SS * BEAM;
    float sc = bem[l] * LOG2E;
    float M = rfl(sc);
    float v = exp2f(sc - M);   // lane l holds v_l, lane0-normalized

    const uint4* Trow = (const uint4*)(Tbuf + (size_t)b * (SS - 1) * (BEAM * BEAM)) + (size_t)l * 8;

    uint4 b0[8], b1[8], b2[8], b3[8];

#define LOADT(BUF, STP) do { \
    const uint4* _p = Trow + (size_t)(STP) * 512; \
    _Pragma("unroll") \
    for (int i = 0; i < 8; ++i) BUF[i] = _p[i]; \
} while (0)

    LOADT(b0, 0); LOADT(b1, 1); LOADT(b2, 2); LOADT(b3, 3);

#define STEP(BUF) do { \
    float vn = dpp_xor1(v); \
    half2v ph; ph.x = (_Float16)v; ph.y = (_Float16)vn; \
    float pf = __builtin_bit_cast(float, ph); /* even lanes: (v_l, v_{l+1}) */ \
    float a[8]; \
    _Pragma("unroll") \
    for (int i = 0; i < 8; ++i) { \
        uint4 t = BUF[i]; \
        float ai = fdot2f(rl(pf, 8 * i + 0), __builtin_bit_cast(float, t.x), 0.f); \
        ai = fdot2f(rl(pf, 8 * i + 2), __builtin_bit_cast(float, t.y), ai); \
        ai = fdot2f(rl(pf, 8 * i + 4), __builtin_bit_cast(float, t.z), ai); \
        ai = fdot2f(rl(pf, 8 * i + 6), __builtin_bit_cast(float, t.w), ai); \
        a[i] = ai; \
    } \
    float s = ((a[0] + a[1]) + (a[2] + a[3])) + ((a[4] + a[5]) + (a[6] + a[7])); \
    float v0 = rfl(s); \
    M += __log2f(v0);                  /* off the v-chain */ \
    v = s * __builtin_amdgcn_rcpf(v0); \
} while (0)

    for (int t = 0; t <= 504; t += 4) {
        STEP(b0);
        if (t + 4 < 511) LOADT(b0, t + 4);
        STEP(b1);
        if (t + 5 < 511) LOADT(b1, t + 5);
        STEP(b2);
        if (t + 6 < 511) LOADT(b2, t + 6);
        STEP(b3);
        if (t + 7 < 511) LOADT(b3, t + 7);
    }
    // steps 508, 509, 510
    STEP(b0);
    STEP(b1);
    STEP(b2);

    float s = wavesum(v);
    if (l == 0) denom[b] = (__log2f(s) + M) * LN2;
#undef STEP
#undef LOADT
}

// ---------------- finalize ----------------
__global__ __launch_bounds__(64) void fin_kernel(
    const float* __restrict__ numer, const float* __restrict__ denom,
    float* __restrict__ out)
{
    int tid = threadIdx.x;
    float llh = 0.f;
    if (tid < BB) {
        llh = numer[tid] - denom[tid];
        out[1 + tid] = llh;
    }
    float s = llh;
    #pragma unroll
    for (int off = 4; off > 0; off >>= 1) s += __shfl_xor(s, off, 64);
    if (tid == 0) out[0] = s;
}

extern "C" void kernel_launch(void* const* d_in, const int* in_sizes, int n_in,
                              void* d_out, int out_size, void* d_ws, size_t ws_size,
                              hipStream_t stream) {
    const float* emissions = (const float*)d_in[0];
    const int*   targets   = (const int*)d_in[1];
    const float* E1        = (const float*)d_in[3];
    const float* E2        = (const float*)d_in[4];
    float* out = (float*)d_out;

    char* w = (char*)d_ws;
    float* numer = (float*)w;
    float* denom = numer + 64;
    int*   btgt  = (int*)(w + 512);
    float* bem   = (float*)(w + 512 + (1u << 20));
    unsigned short* Tbuf = (unsigned short*)(w + 512 + (2u << 20));

    num_kernel  <<<BB, 256, 0, stream>>>(emissions, targets, E1, E2, numer);
    topk_kernel <<<BB * SS, 256, 0, stream>>>(emissions, targets, btgt, bem);
    trans_kernel<<<BB * (SS - 1), 256, 0, stream>>>(E1, E2, btgt, bem, Tbuf);
    recur_kernel<<<BB, 64, 0, stream>>>(Tbuf, bem, denom);
    fin_kernel  <<<1, 64, 0, stream>>>(numer, denom, out);
}

// Round 4
// 851.336 us; speedup vs baseline: 1.5529x; 1.1393x over previous
//
#include <hip/hip_runtime.h>
#include <hip/hip_bf16.h>

#define VOCAB 32000
#define RANK  32
#define BEAM  64
#define BB    8
#define SS    512
#define KSEL  63   // beam slots besides the forced target
#define NPAIR 256  // 255 folded pairs + 1 single (t=510) per batch

#define LOG2E 1.4426950408889634f
#define LN2   0.6931471805599453f

typedef _Float16 half2v __attribute__((ext_vector_type(2)));
typedef _Float16 half4  __attribute__((ext_vector_type(4)));
typedef _Float16 half8  __attribute__((ext_vector_type(8)));
typedef float    f32x4  __attribute__((ext_vector_type(4)));

__device__ __forceinline__ unsigned sortkey(float f) {
    unsigned u = __float_as_uint(f);
    return u ^ (((unsigned)((int)u >> 31)) | 0x80000000u);
}
__device__ __forceinline__ float keyfloat(unsigned k) {
    unsigned u = (k & 0x80000000u) ? (k ^ 0x80000000u) : ~k;
    return __uint_as_float(u);
}
__device__ __forceinline__ float wavesum(float x) {
    #pragma unroll
    for (int off = 32; off > 0; off >>= 1) x += __shfl_xor(x, off, 64);
    return x;
}
__device__ __forceinline__ float rl(float x, int lane) {
    return __builtin_bit_cast(float, __builtin_amdgcn_readlane(__builtin_bit_cast(int, x), lane));
}
__device__ __forceinline__ float rfl(float x) {
    return __builtin_bit_cast(float, __builtin_amdgcn_readfirstlane(__builtin_bit_cast(int, x)));
}
__device__ __forceinline__ float fdot2f(float a, float b, float c) {
#if __has_builtin(__builtin_amdgcn_fdot2)
    return __builtin_amdgcn_fdot2(__builtin_bit_cast(half2v, a),
                                  __builtin_bit_cast(half2v, b), c, false);
#else
    half2v ha = __builtin_bit_cast(half2v, a), hb = __builtin_bit_cast(half2v, b);
    return fmaf((float)ha.x, (float)hb.x, fmaf((float)ha.y, (float)hb.y, c));
#endif
}
// lane^1 neighbor exchange, 1 VALU op (quad_perm [1,0,3,2])
__device__ __forceinline__ float dpp_xor1(float x) {
#if __has_builtin(__builtin_amdgcn_mov_dpp)
    return __builtin_bit_cast(float,
        __builtin_amdgcn_mov_dpp(__builtin_bit_cast(int, x), 0xB1, 0xF, 0xF, true));
#else
    return __shfl_xor(x, 1, 64);
#endif
}
__device__ __forceinline__ half8 loadrow_h8(const float* __restrict__ p) {
    half8 h;
    #pragma unroll
    for (int j = 0; j < 8; ++j) h[j] = (_Float16)p[j];
    return h;
}

// ---------------- numerator ----------------
__global__ __launch_bounds__(256) void num_kernel(
    const float* __restrict__ emissions, const int* __restrict__ targets,
    const float* __restrict__ E1, const float* __restrict__ E2,
    float* __restrict__ numer)
{
    int b = blockIdx.x, tid = threadIdx.x;
    float acc = 0.f;
    for (int s = tid; s < SS; s += 256) {
        int t = targets[b * SS + s];
        acc += emissions[((size_t)(b * SS + s)) * VOCAB + t];
        if (s > 0) {
            int tp = targets[b * SS + s - 1];
            const float* r1 = E1 + (size_t)tp * RANK;
            const float* r2 = E2 + (size_t)t * RANK;
            float d = 0.f;
            #pragma unroll
            for (int r = 0; r < RANK; ++r) d = fmaf(r1[r], r2[r], d);
            acc += d;
        }
    }
    __shared__ float red[256];
    red[tid] = acc;
    __syncthreads();
    for (int w = 128; w >= 1; w >>= 1) {
        if (tid < w) red[tid] += red[tid + w];
        __syncthreads();
    }
    if (tid == 0) numer[b] = red[0];
}

// ---------------- parallel threshold selection from an LDS histogram ----------
template<int NB>
__device__ __forceinline__ void select_from_hist(
    const unsigned* hist, unsigned need,
    unsigned* wsum /*[4] LDS*/, unsigned* result /*[2] LDS*/)
{
    constexpr int BPT = NB / 256;
    const int tid  = threadIdx.x;
    const int lane = tid & 63, wid = tid >> 6;
    const int base = tid * BPT;

    unsigned local = 0;
    #pragma unroll
    for (int i = 0; i < BPT; ++i) local += hist[base + i];

    unsigned x = local;
    #pragma unroll
    for (int off = 1; off < 64; off <<= 1) {
        unsigned v = __shfl_down(x, off, 64);
        x += (lane + off < 64) ? v : 0u;
    }
    if (lane == 0) wsum[wid] = x;
    __syncthreads();

    unsigned add = 0;
    #pragma unroll
    for (int w = 0; w < 4; ++w) add += (w > wid) ? wsum[w] : 0u;

    const unsigned S_incl = x + add;
    const unsigned S_excl = S_incl - local;
    if (S_excl < need && S_incl >= need) {
        unsigned cum = S_excl;
        #pragma unroll
        for (int i = BPT - 1; i >= 0; --i) {
            unsigned h = hist[base + i];
            if (cum + h >= need) { result[0] = (unsigned)(base + i); result[1] = need - cum; break; }
            cum += h;
        }
    }
    __syncthreads();
}

// ---------------- exact top-64 per (b,s) ----------------
// LDS diet vs prior version: 11-bit level-1 hist (2048 bins) + CCAP 512
// -> ~12.4 KB LDS -> 8 blocks/CU (wave-capped) = 100% occupancy.
// Key split: 11 (31:21) + 11 (20:10) + 10 (9:0) = 32 bits exact.
#define CCAP 512
__global__ __launch_bounds__(256) void topk_kernel(
    const float* __restrict__ emissions, const int* __restrict__ targets,
    int* __restrict__ beam_tgt, float* __restrict__ beam_em)
{
    __shared__ unsigned hist[2048];
    __shared__ unsigned s_ws[4];
    __shared__ unsigned s_sel[2];
    __shared__ unsigned s_cnt[2];
    __shared__ unsigned s_ccount;
    __shared__ unsigned ckey[CCAP];
    __shared__ unsigned cidx[CCAP];

    const int bs  = blockIdx.x;
    const int tid = threadIdx.x;
    const float* row = emissions + (size_t)bs * VOCAB;
    const int tgt = targets[bs];

    for (int i = tid; i < 2048; i += 256) hist[i] = 0;
    if (tid == 0) { s_ccount = 0; s_cnt[0] = 1; s_cnt[1] = 0; }
    __syncthreads();

    // pass 1: 11-bit histogram of sort keys
    for (int i4 = tid; i4 < VOCAB / 4; i4 += 256) {
        float4 v = ((const float4*)row)[i4];
        int base = i4 * 4;
        #pragma unroll
        for (int j = 0; j < 4; ++j) {
            float f = (j == 0) ? v.x : (j == 1) ? v.y : (j == 2) ? v.z : v.w;
            int idx = base + j;
            if (idx != tgt) atomicAdd(&hist[sortkey(f) >> 21], 1u);
        }
    }
    __syncthreads();

    select_from_hist<2048>(hist, KSEL, s_ws, s_sel);
    const unsigned b1 = s_sel[0], need1 = s_sel[1];

    int*   bt = beam_tgt + (size_t)bs * BEAM;
    float* be = beam_em  + (size_t)bs * BEAM;

    // pass 2: emit certain winners, capture threshold-bin candidates
    for (int i4 = tid; i4 < VOCAB / 4; i4 += 256) {
        float4 v = ((const float4*)row)[i4];
        int base = i4 * 4;
        #pragma unroll
        for (int j = 0; j < 4; ++j) {
            float f = (j == 0) ? v.x : (j == 1) ? v.y : (j == 2) ? v.z : v.w;
            int idx = base + j;
            if (idx == tgt) continue;
            unsigned key = sortkey(f);
            unsigned bin = key >> 21;
            if (bin > b1) {
                unsigned p = atomicAdd(&s_cnt[0], 1u);
                if (p < BEAM) { bt[p] = idx; be[p] = f; }
            } else if (bin == b1) {
                unsigned c = atomicAdd(&s_ccount, 1u);
                if (c < CCAP) { ckey[c] = key; cidx[c] = idx; }
            }
        }
    }
    __syncthreads();
    const unsigned C = min(s_ccount, (unsigned)CCAP);

    // level-2: 11-bit histogram (key bits 20:10) over candidates
    for (int i = tid; i < 2048; i += 256) hist[i] = 0;
    __syncthreads();
    for (int i = tid; i < (int)C; i += 256) atomicAdd(&hist[(ckey[i] >> 10) & 2047], 1u);
    __syncthreads();
    select_from_hist<2048>(hist, need1, s_ws, s_sel);
    const unsigned b2 = s_sel[0], need2 = s_sel[1];

    // level-3: 10-bit histogram (key bits 9:0) within bin b2
    for (int i = tid; i < 1024; i += 256) hist[i] = 0;
    __syncthreads();
    for (int i = tid; i < (int)C; i += 256) {
        unsigned k = ckey[i];
        if (((k >> 10) & 2047) == b2) atomicAdd(&hist[k & 1023], 1u);
    }
    __syncthreads();
    select_from_hist<1024>(hist, need2, s_ws, s_sel);
    const unsigned Kthr = (b1 << 21) | (b2 << 10) | s_sel[0];
    const unsigned tieNeed = s_sel[1];

    for (int i = tid; i < (int)C; i += 256) {
        unsigned k = ckey[i];
        if (k > Kthr) {
            unsigned p = atomicAdd(&s_cnt[0], 1u);
            if (p < BEAM) { bt[p] = cidx[i]; be[p] = keyfloat(k); }
        } else if (k == Kthr) {
            unsigned t = atomicAdd(&s_cnt[1], 1u);
            if (t < tieNeed) {
                unsigned p = atomicAdd(&s_cnt[0], 1u);
                if (p < BEAM) { bt[p] = cidx[i]; be[p] = keyfloat(k); }
            }
        }
    }
    if (tid == 0) { bt[0] = tgt; be[0] = row[tgt]; }
}

// ---------------- pair-fold kernel -------------------------------------------
// For pair i<255: P_i = T''_{2i+1} . T''_{2i}  (64x64, f16, scaled by 2^-e),
// where T''_t[l][k] = exp(sum_r E2[beam_{t+1}[l]][r]*E1[beam_t[k]][r] + em_{t+1}[l]).
// Consumed by recur as v' = P v  (two steps at once). e stored to scl (log2 units).
// For i==255: single T''_510, unscaled (e=0).
// MFMA conventions (m89-verified): mfma(A-rows=X, B-rows=Y) -> D[x][y] = sum X[x].Y[y];
// frag: row=lane&15, elems (lane>>4)*8+j; D: col=lane&15, row=(lane>>4)*4+reg.
__global__ __launch_bounds__(256) void pair_kernel(
    const float* __restrict__ E1, const float* __restrict__ E2,
    const int* __restrict__ beam_tgt, const float* __restrict__ beam_em,
    unsigned short* __restrict__ Pbuf, float* __restrict__ scl)
{
    const int blk = blockIdx.x;
    const int b = blk >> 8, i = blk & 255;
    const int tid  = threadIdx.x;
    const int w    = tid >> 6;
    const int lane = tid & 63;
    const int hl   = lane & 15;
    const int kg   = lane >> 4;

    unsigned short* out = Pbuf + ((size_t)(b * NPAIR + i)) * (BEAM * BEAM);

    if (i == 255) {
        // single step t1=510: D[l][k], store row-major [l][k]
        const int* btk = beam_tgt + ((size_t)(b * SS + 510)) * BEAM;
        const int* btl = btk + BEAM;
        const float* em = beam_em + ((size_t)(b * SS + 511)) * BEAM;

        half8 afrag = loadrow_h8(E2 + (size_t)btl[w * 16 + hl] * RANK + kg * 8);
        float emv[4];
        #pragma unroll
        for (int q = 0; q < 4; ++q) emv[q] = em[w * 16 + kg * 4 + q];

        #pragma unroll
        for (int t = 0; t < 4; ++t) {
            half8 bfrag = loadrow_h8(E1 + (size_t)btk[t * 16 + hl] * RANK + kg * 8);
            f32x4 acc = {0.f, 0.f, 0.f, 0.f};
            acc = __builtin_amdgcn_mfma_f32_16x16x32_f16(afrag, bfrag, acc, 0, 0, 0);
            #pragma unroll
            for (int q = 0; q < 4; ++q) {
                int lg  = w * 16 + kg * 4 + q;
                int kgc = t * 16 + hl;
                _Float16 h = (_Float16)exp2f((acc[q] + emv[q]) * LOG2E);
                out[(size_t)lg * BEAM + kgc] = __builtin_bit_cast(unsigned short, h);
            }
        }
        if (tid == 0) scl[(size_t)b * NPAIR + i] = 0.f;
        return;
    }

    // pair i: steps t=2i (beams A->B) and t=2i+1 (beams B->C)
    const int* btA = beam_tgt + ((size_t)(b * SS + 2 * i)) * BEAM;  // from (k)
    const int* btB = btA + BEAM;                                    // mid  (m)
    const int* btC = btB + BEAM;                                    // to   (l)
    const float* emB = beam_em + ((size_t)(b * SS + 2 * i + 1)) * BEAM;
    const float* emC = emB + BEAM;

    __shared__ _Float16 T1t[64][72];   // T1t[k][m] = T1[m][k]   (+8 pad: 2-way banks)
    __shared__ _Float16 T2r[64][72];   // T2r[l][m] = T2[l][m]
    __shared__ float smax[4];

    // Phase A: T1[m][k] = sum_r E2[btB[m]].E1[btA[k]] ; D[m][k] -> store T1t[k][m]
    // Phase B: T2[l][m] = sum_r E2[btC[l]].E1[btB[m]] ; D[m][l] -> store T2r[l][m]
    half8 afrag1 = loadrow_h8(E2 + (size_t)btB[w * 16 + hl] * RANK + kg * 8); // m-rows, E2
    half8 afrag2 = loadrow_h8(E1 + (size_t)btB[w * 16 + hl] * RANK + kg * 8); // m-rows, E1
    float em1v[4];
    #pragma unroll
    for (int q = 0; q < 4; ++q) em1v[q] = emB[w * 16 + kg * 4 + q];  // em of to-beam m

    #pragma unroll
    for (int t = 0; t < 4; ++t) {
        half8 bfrag = loadrow_h8(E1 + (size_t)btA[t * 16 + hl] * RANK + kg * 8); // k-rows
        f32x4 acc = {0.f, 0.f, 0.f, 0.f};
        acc = __builtin_amdgcn_mfma_f32_16x16x32_f16(afrag1, bfrag, acc, 0, 0, 0);
        half4 hv;
        #pragma unroll
        for (int q = 0; q < 4; ++q) hv[q] = (_Float16)exp2f((acc[q] + em1v[q]) * LOG2E);
        *(half4*)&T1t[t * 16 + hl][w * 16 + kg * 4] = hv;   // [k][m], 4 consecutive m
    }
    #pragma unroll
    for (int t = 0; t < 4; ++t) {
        half8 bfrag = loadrow_h8(E2 + (size_t)btC[t * 16 + hl] * RANK + kg * 8); // l-rows
        float em2 = emC[t * 16 + hl];                     // em of to-beam l
        f32x4 acc = {0.f, 0.f, 0.f, 0.f};
        acc = __builtin_amdgcn_mfma_f32_16x16x32_f16(afrag2, bfrag, acc, 0, 0, 0);
        half4 hv;
        #pragma unroll
        for (int q = 0; q < 4; ++q) hv[q] = (_Float16)exp2f((acc[q] + em2) * LOG2E);
        *(half4*)&T2r[t * 16 + hl][w * 16 + kg * 4] = hv;   // [l][m], 4 consecutive m
    }
    __syncthreads();

    // Phase C: D2[k][l] = sum_m T1t[k][m]*T2r[l][m] = P[l][k], K=64 via 2 MFMA.
    const int ra = w * 16 + hl;
    half8 a0 = *(const half8*)&T1t[ra][kg * 8];
    half8 a1 = *(const half8*)&T1t[ra][32 + kg * 8];
    f32x4 pacc[4];
    float mp = -1e30f;
    #pragma unroll
    for (int t = 0; t < 4; ++t) {
        half8 c0 = *(const half8*)&T2r[t * 16 + hl][kg * 8];
        half8 c1 = *(const half8*)&T2r[t * 16 + hl][32 + kg * 8];
        f32x4 acc = {0.f, 0.f, 0.f, 0.f};
        acc = __builtin_amdgcn_mfma_f32_16x16x32_f16(a0, c0, acc, 0, 0, 0);
        acc = __builtin_amdgcn_mfma_f32_16x16x32_f16(a1, c1, acc, 0, 0, 0);
        pacc[t] = acc;
        #pragma unroll
        for (int q = 0; q < 4; ++q) mp = fmaxf(mp, acc[q]);
    }

    // block max -> power-of-2 scale; e absorbed back in recur (M += log2(v0) + e)
    #pragma unroll
    for (int off = 32; off > 0; off >>= 1) mp = fmaxf(mp, __shfl_xor(mp, off, 64));
    if (lane == 0) smax[w] = mp;
    __syncthreads();
    float mx = fmaxf(fmaxf(smax[0], smax[1]), fmaxf(smax[2], smax[3]));
    float e  = ceilf(__log2f(mx));
    float c  = exp2f(-e);
    if (tid == 0) scl[(size_t)b * NPAIR + i] = e;

    #pragma unroll
    for (int t = 0; t < 4; ++t) {
        half4 hv;
        #pragma unroll
        for (int q = 0; q < 4; ++q) hv[q] = (_Float16)(pacc[t][q] * c);
        // P[l][k]: l = t*16+hl (fixed), k = w*16+kg*4+q (4 consecutive) -> 8B store
        *(half4*)(out + (size_t)(t * 16 + hl) * BEAM + w * 16 + kg * 4) = hv;
    }
}

// ---------------- sequential beam recursion, 1 wave per batch ----------------
// Now NPAIR=256 steps (half the depth, half the bytes). v' = P v; renorm by v0;
// per-pair scale e re-added to M off the critical chain.
__global__ __launch_bounds__(64) void recur_kernel(
    const unsigned short* __restrict__ Pbuf, const float* __restrict__ beam_em,
    const float* __restrict__ scl, float* __restrict__ denom)
{
    int b = blockIdx.x, l = threadIdx.x;
    const float* bem = beam_em + (size_t)b * SS * BEAM;
    const float* scb = scl + (size_t)b * NPAIR;
    float sc = bem[l] * LOG2E;
    float M = rfl(sc);
    float v = exp2f(sc - M);   // lane l holds v_l, lane0-normalized

    const uint4* Trow = (const uint4*)(Pbuf + (size_t)b * NPAIR * (BEAM * BEAM)) + (size_t)l * 8;

    uint4 b0[8], b1[8], b2[8], b3[8];
    float l0, l1, l2, l3;

#define LOADT(BUF, STP) do { \
    const uint4* _p = Trow + (size_t)(STP) * 512; \
    _Pragma("unroll") \
    for (int i = 0; i < 8; ++i) BUF[i] = _p[i]; \
} while (0)

    LOADT(b0, 0); LOADT(b1, 1); LOADT(b2, 2); LOADT(b3, 3);
    l0 = scb[0]; l1 = scb[1]; l2 = scb[2]; l3 = scb[3];

#define STEP(BUF, LC) do { \
    float vn = dpp_xor1(v); \
    half2v ph; ph.x = (_Float16)v; ph.y = (_Float16)vn; \
    float pf = __builtin_bit_cast(float, ph); /* even lanes: (v_l, v_{l+1}) */ \
    float a[8]; \
    _Pragma("unroll") \
    for (int i = 0; i < 8; ++i) { \
        uint4 t = BUF[i]; \
        float ai = fdot2f(rl(pf, 8 * i + 0), __builtin_bit_cast(float, t.x), 0.f); \
        ai = fdot2f(rl(pf, 8 * i + 2), __builtin_bit_cast(float, t.y), ai); \
        ai = fdot2f(rl(pf, 8 * i + 4), __builtin_bit_cast(float, t.z), ai); \
        ai = fdot2f(rl(pf, 8 * i + 6), __builtin_bit_cast(float, t.w), ai); \
        a[i] = ai; \
    } \
    float s = ((a[0] + a[1]) + (a[2] + a[3])) + ((a[4] + a[5]) + (a[6] + a[7])); \
    float v0 = rfl(s); \
    M += __log2f(v0) + (LC);           /* off the v-chain; restores 2^-e scale */ \
    v = s * __builtin_amdgcn_rcpf(v0); \
} while (0)

    for (int t = 0; t < 252; t += 4) {
        STEP(b0, l0); LOADT(b0, t + 4); l0 = scb[t + 4];
        STEP(b1, l1); LOADT(b1, t + 5); l1 = scb[t + 5];
        STEP(b2, l2); LOADT(b2, t + 6); l2 = scb[t + 6];
        STEP(b3, l3); LOADT(b3, t + 7); l3 = scb[t + 7];
    }
    // steps 252..255
    STEP(b0, l0);
    STEP(b1, l1);
    STEP(b2, l2);
    STEP(b3, l3);

    float s = wavesum(v);
    if (l == 0) denom[b] = (__log2f(s) + M) * LN2;
#undef STEP
#undef LOADT
}

// ---------------- finalize ----------------
__global__ __launch_bounds__(64) void fin_kernel(
    const float* __restrict__ numer, const float* __restrict__ denom,
    float* __restrict__ out)
{
    int tid = threadIdx.x;
    float llh = 0.f;
    if (tid < BB) {
        llh = numer[tid] - denom[tid];
        out[1 + tid] = llh;
    }
    float s = llh;
    #pragma unroll
    for (int off = 4; off > 0; off >>= 1) s += __shfl_xor(s, off, 64);
    if (tid == 0) out[0] = s;
}

extern "C" void kernel_launch(void* const* d_in, const int* in_sizes, int n_in,
                              void* d_out, int out_size, void* d_ws, size_t ws_size,
                              hipStream_t stream) {
    const float* emissions = (const float*)d_in[0];
    const int*   targets   = (const int*)d_in[1];
    const float* E1        = (const float*)d_in[3];
    const float* E2        = (const float*)d_in[4];
    float* out = (float*)d_out;

    char* w = (char*)d_ws;
    float* numer = (float*)w;                               // 32 B
    float* denom = (float*)(w + 256);                       // 32 B
    float* scl   = (float*)(w + 1024);                      // 8 KB
    int*   btgt  = (int*)(w + 16384);                       // 1 MiB
    float* bem   = (float*)(w + 16384 + (1u << 20));        // 1 MiB
    unsigned short* Pbuf = (unsigned short*)(w + 16384 + (2u << 20)); // 16 MiB

    num_kernel  <<<BB, 256, 0, stream>>>(emissions, targets, E1, E2, numer);
    topk_kernel <<<BB * SS, 256, 0, stream>>>(emissions, targets, btgt, bem);
    pair_kernel <<<BB * NPAIR, 256, 0, stream>>>(E1, E2, btgt, bem, Pbuf, scl);
    recur_kernel<<<BB, 64, 0, stream>>>(Pbuf, bem, scl, denom);
    fin_kernel  <<<1, 64, 0, stream>>>(numer, denom, out);
}

// Round 5
// 747.824 us; speedup vs baseline: 1.7679x; 1.1384x over previous
//
#include <hip/hip_runtime.h>
#include <hip/hip_bf16.h>

#define VOCAB 32000
#define RANK  32
#define BEAM  64
#define BB    8
#define SS    512
#define KSEL  63   // beam slots besides the forced target
#define NPAIR 256  // 255 folded pairs + 1 single (t=510) per batch
#define NQUAD 128
#define NOCT  64

#define LOG2E 1.4426950408889634f
#define LN2   0.6931471805599453f

typedef _Float16 half2v __attribute__((ext_vector_type(2)));
typedef _Float16 half4  __attribute__((ext_vector_type(4)));
typedef _Float16 half8  __attribute__((ext_vector_type(8)));
typedef float    f32x4  __attribute__((ext_vector_type(4)));

__device__ __forceinline__ unsigned sortkey(float f) {
    unsigned u = __float_as_uint(f);
    return u ^ (((unsigned)((int)u >> 31)) | 0x80000000u);
}
__device__ __forceinline__ float keyfloat(unsigned k) {
    unsigned u = (k & 0x80000000u) ? (k ^ 0x80000000u) : ~k;
    return __uint_as_float(u);
}
__device__ __forceinline__ float wavesum(float x) {
    #pragma unroll
    for (int off = 32; off > 0; off >>= 1) x += __shfl_xor(x, off, 64);
    return x;
}
__device__ __forceinline__ float rl(float x, int lane) {
    return __builtin_bit_cast(float, __builtin_amdgcn_readlane(__builtin_bit_cast(int, x), lane));
}
__device__ __forceinline__ float rfl(float x) {
    return __builtin_bit_cast(float, __builtin_amdgcn_readfirstlane(__builtin_bit_cast(int, x)));
}
__device__ __forceinline__ float fdot2f(float a, float b, float c) {
#if __has_builtin(__builtin_amdgcn_fdot2)
    return __builtin_amdgcn_fdot2(__builtin_bit_cast(half2v, a),
                                  __builtin_bit_cast(half2v, b), c, false);
#else
    half2v ha = __builtin_bit_cast(half2v, a), hb = __builtin_bit_cast(half2v, b);
    return fmaf((float)ha.x, (float)hb.x, fmaf((float)ha.y, (float)hb.y, c));
#endif
}
// lane^1 neighbor exchange, 1 VALU op (quad_perm [1,0,3,2])
__device__ __forceinline__ float dpp_xor1(float x) {
#if __has_builtin(__builtin_amdgcn_mov_dpp)
    return __builtin_bit_cast(float,
        __builtin_amdgcn_mov_dpp(__builtin_bit_cast(int, x), 0xB1, 0xF, 0xF, true));
#else
    return __shfl_xor(x, 1, 64);
#endif
}
__device__ __forceinline__ half8 loadrow_h8(const float* __restrict__ p) {
    half8 h;
    #pragma unroll
    for (int j = 0; j < 8; ++j) h[j] = (_Float16)p[j];
    return h;
}

// ---------------- numerator ----------------
__global__ __launch_bounds__(256) void num_kernel(
    const float* __restrict__ emissions, const int* __restrict__ targets,
    const float* __restrict__ E1, const float* __restrict__ E2,
    float* __restrict__ numer)
{
    int b = blockIdx.x, tid = threadIdx.x;
    float acc = 0.f;
    for (int s = tid; s < SS; s += 256) {
        int t = targets[b * SS + s];
        acc += emissions[((size_t)(b * SS + s)) * VOCAB + t];
        if (s > 0) {
            int tp = targets[b * SS + s - 1];
            const float* r1 = E1 + (size_t)tp * RANK;
            const float* r2 = E2 + (size_t)t * RANK;
            float d = 0.f;
            #pragma unroll
            for (int r = 0; r < RANK; ++r) d = fmaf(r1[r], r2[r], d);
            acc += d;
        }
    }
    __shared__ float red[256];
    red[tid] = acc;
    __syncthreads();
    for (int w = 128; w >= 1; w >>= 1) {
        if (tid < w) red[tid] += red[tid + w];
        __syncthreads();
    }
    if (tid == 0) numer[b] = red[0];
}

// ---------------- parallel threshold selection from an LDS histogram ----------
template<int NB>
__device__ __forceinline__ void select_from_hist(
    const unsigned* hist, unsigned need,
    unsigned* wsum /*[4] LDS*/, unsigned* result /*[2] LDS*/)
{
    constexpr int BPT = NB / 256;
    const int tid  = threadIdx.x;
    const int lane = tid & 63, wid = tid >> 6;
    const int base = tid * BPT;

    unsigned local = 0;
    #pragma unroll
    for (int i = 0; i < BPT; ++i) local += hist[base + i];

    unsigned x = local;
    #pragma unroll
    for (int off = 1; off < 64; off <<= 1) {
        unsigned v = __shfl_down(x, off, 64);
        x += (lane + off < 64) ? v : 0u;
    }
    if (lane == 0) wsum[wid] = x;
    __syncthreads();

    unsigned add = 0;
    #pragma unroll
    for (int w = 0; w < 4; ++w) add += (w > wid) ? wsum[w] : 0u;

    const unsigned S_incl = x + add;
    const unsigned S_excl = S_incl - local;
    if (S_excl < need && S_incl >= need) {
        unsigned cum = S_excl;
        #pragma unroll
        for (int i = BPT - 1; i >= 0; --i) {
            unsigned h = hist[base + i];
            if (cum + h >= need) { result[0] = (unsigned)(base + i); result[1] = need - cum; break; }
            cum += h;
        }
    }
    __syncthreads();
}

// ---------------- exact top-64 per (b,s), single HBM pass -------------------
// Pass 1 builds the 11-bit histogram AND stashes all elements with
// bin >= STASH_BIN (value >= 2.5, bin-aligned). If the exact threshold bin
// b1 >= STASH_BIN and the stash didn't overflow (always true for N(0,1):
// 63rd of 32000 ~ 2.88, E[stash] ~ 200 << 512), winners and candidates come
// from the stash -- no second pass. Exact fallback (global pass 2) otherwise.
// Key split: 11 (31:21) + 11 (20:10) + 10 (9:0) = 32 bits exact.
#define CCAP 512
#define SCAP 512
#define STASH_BIN 1537u   // sortkey(2.5f)>>21 : 0x40200000^0x80000000 = 0xC0200000
__global__ __launch_bounds__(256) void topk_kernel(
    const float* __restrict__ emissions, const int* __restrict__ targets,
    int* __restrict__ beam_tgt, float* __restrict__ beam_em)
{
    __shared__ unsigned hist[2048];
    __shared__ unsigned s_ws[4];
    __shared__ unsigned s_sel[2];
    __shared__ unsigned s_cnt[2];
    __shared__ unsigned s_ccount;
    __shared__ unsigned s_scount;
    __shared__ unsigned skey[SCAP];
    __shared__ unsigned sidx[SCAP];
    __shared__ unsigned ckey[CCAP];
    __shared__ unsigned cidx[CCAP];

    const int bs  = blockIdx.x;
    const int tid = threadIdx.x;
    const float* row = emissions + (size_t)bs * VOCAB;
    const int tgt = targets[bs];

    for (int i = tid; i < 2048; i += 256) hist[i] = 0;
    if (tid == 0) { s_ccount = 0; s_scount = 0; s_cnt[0] = 1; s_cnt[1] = 0; }
    __syncthreads();

    // pass 1: histogram + high-value stash
    for (int i4 = tid; i4 < VOCAB / 4; i4 += 256) {
        float4 v = ((const float4*)row)[i4];
        int base = i4 * 4;
        #pragma unroll
        for (int j = 0; j < 4; ++j) {
            float f = (j == 0) ? v.x : (j == 1) ? v.y : (j == 2) ? v.z : v.w;
            int idx = base + j;
            if (idx == tgt) continue;
            unsigned key = sortkey(f);
            unsigned bin = key >> 21;
            atomicAdd(&hist[bin], 1u);
            if (bin >= STASH_BIN) {
                unsigned c = atomicAdd(&s_scount, 1u);
                if (c < SCAP) { skey[c] = key; sidx[c] = idx; }
            }
        }
    }
    __syncthreads();

    select_from_hist<2048>(hist, KSEL, s_ws, s_sel);
    const unsigned b1 = s_sel[0], need1 = s_sel[1];

    int*   bt = beam_tgt + (size_t)bs * BEAM;
    float* be = beam_em  + (size_t)bs * BEAM;

    const bool fast = (b1 >= STASH_BIN) && (s_scount <= SCAP);

    if (fast) {
        // winners + candidates straight from the stash (complete by construction)
        const unsigned S = s_scount;
        for (int i = tid; i < (int)S; i += 256) {
            unsigned k = skey[i], bin = k >> 21;
            if (bin > b1) {
                unsigned p = atomicAdd(&s_cnt[0], 1u);
                if (p < BEAM) { bt[p] = sidx[i]; be[p] = keyfloat(k); }
            } else if (bin == b1) {
                unsigned c = atomicAdd(&s_ccount, 1u);   // <= SCAP == CCAP
                ckey[c] = k; cidx[c] = sidx[i];
            }
        }
    } else {
        // exact fallback: re-read the row
        for (int i4 = tid; i4 < VOCAB / 4; i4 += 256) {
            float4 v = ((const float4*)row)[i4];
            int base = i4 * 4;
            #pragma unroll
            for (int j = 0; j < 4; ++j) {
                float f = (j == 0) ? v.x : (j == 1) ? v.y : (j == 2) ? v.z : v.w;
                int idx = base + j;
                if (idx == tgt) continue;
                unsigned key = sortkey(f);
                unsigned bin = key >> 21;
                if (bin > b1) {
                    unsigned p = atomicAdd(&s_cnt[0], 1u);
                    if (p < BEAM) { bt[p] = idx; be[p] = f; }
                } else if (bin == b1) {
                    unsigned c = atomicAdd(&s_ccount, 1u);
                    if (c < CCAP) { ckey[c] = key; cidx[c] = idx; }
                }
            }
        }
    }
    __syncthreads();
    const unsigned C = min(s_ccount, (unsigned)CCAP);

    // level-2: 11-bit histogram (key bits 20:10) over candidates
    for (int i = tid; i < 2048; i += 256) hist[i] = 0;
    __syncthreads();
    for (int i = tid; i < (int)C; i += 256) atomicAdd(&hist[(ckey[i] >> 10) & 2047], 1u);
    __syncthreads();
    select_from_hist<2048>(hist, need1, s_ws, s_sel);
    const unsigned b2 = s_sel[0], need2 = s_sel[1];

    // level-3: 10-bit histogram (key bits 9:0) within bin b2
    for (int i = tid; i < 1024; i += 256) hist[i] = 0;
    __syncthreads();
    for (int i = tid; i < (int)C; i += 256) {
        unsigned k = ckey[i];
        if (((k >> 10) & 2047) == b2) atomicAdd(&hist[k & 1023], 1u);
    }
    __syncthreads();
    select_from_hist<1024>(hist, need2, s_ws, s_sel);
    const unsigned Kthr = (b1 << 21) | (b2 << 10) | s_sel[0];
    const unsigned tieNeed = s_sel[1];

    for (int i = tid; i < (int)C; i += 256) {
        unsigned k = ckey[i];
        if (k > Kthr) {
            unsigned p = atomicAdd(&s_cnt[0], 1u);
            if (p < BEAM) { bt[p] = cidx[i]; be[p] = keyfloat(k); }
        } else if (k == Kthr) {
            unsigned t = atomicAdd(&s_cnt[1], 1u);
            if (t < tieNeed) {
                unsigned p = atomicAdd(&s_cnt[0], 1u);
                if (p < BEAM) { bt[p] = cidx[i]; be[p] = keyfloat(k); }
            }
        }
    }
    if (tid == 0) { bt[0] = tgt; be[0] = row[tgt]; }
}

// ---------------- pair-fold kernel -------------------------------------------
// For pair i<255: P_i = T''_{2i+1} . T''_{2i}  (64x64, f16, scaled by 2^-e),
// where T''_t[l][k] = exp(sum_r E2[beam_{t+1}[l]][r]*E1[beam_t[k]][r] + em_{t+1}[l]).
// For i==255: single T''_510, unscaled (e=0).
// MFMA conventions (m89-verified): mfma(A-rows=X, B-rows=Y) -> D[x][y] = sum X[x].Y[y];
// frag: row=lane&15, elems (lane>>4)*8+j; D: col=lane&15, row=(lane>>4)*4+reg.
__global__ __launch_bounds__(256) void pair_kernel(
    const float* __restrict__ E1, const float* __restrict__ E2,
    const int* __restrict__ beam_tgt, const float* __restrict__ beam_em,
    unsigned short* __restrict__ Pbuf, float* __restrict__ scl)
{
    const int blk = blockIdx.x;
    const int b = blk >> 8, i = blk & 255;
    const int tid  = threadIdx.x;
    const int w    = tid >> 6;
    const int lane = tid & 63;
    const int hl   = lane & 15;
    const int kg   = lane >> 4;

    unsigned short* out = Pbuf + ((size_t)(b * NPAIR + i)) * (BEAM * BEAM);

    if (i == 255) {
        const int* btk = beam_tgt + ((size_t)(b * SS + 510)) * BEAM;
        const int* btl = btk + BEAM;
        const float* em = beam_em + ((size_t)(b * SS + 511)) * BEAM;

        half8 afrag = loadrow_h8(E2 + (size_t)btl[w * 16 + hl] * RANK + kg * 8);
        float emv[4];
        #pragma unroll
        for (int q = 0; q < 4; ++q) emv[q] = em[w * 16 + kg * 4 + q];

        #pragma unroll
        for (int t = 0; t < 4; ++t) {
            half8 bfrag = loadrow_h8(E1 + (size_t)btk[t * 16 + hl] * RANK + kg * 8);
            f32x4 acc = {0.f, 0.f, 0.f, 0.f};
            acc = __builtin_amdgcn_mfma_f32_16x16x32_f16(afrag, bfrag, acc, 0, 0, 0);
            #pragma unroll
            for (int q = 0; q < 4; ++q) {
                int lg  = w * 16 + kg * 4 + q;
                int kgc = t * 16 + hl;
                _Float16 h = (_Float16)exp2f((acc[q] + emv[q]) * LOG2E);
                out[(size_t)lg * BEAM + kgc] = __builtin_bit_cast(unsigned short, h);
            }
        }
        if (tid == 0) scl[(size_t)b * NPAIR + i] = 0.f;
        return;
    }

    const int* btA = beam_tgt + ((size_t)(b * SS + 2 * i)) * BEAM;  // from (k)
    const int* btB = btA + BEAM;                                    // mid  (m)
    const int* btC = btB + BEAM;                                    // to   (l)
    const float* emB = beam_em + ((size_t)(b * SS + 2 * i + 1)) * BEAM;
    const float* emC = emB + BEAM;

    __shared__ _Float16 T1t[64][72];   // T1t[k][m] = T1[m][k]
    __shared__ _Float16 T2r[64][72];   // T2r[l][m] = T2[l][m]
    __shared__ float smax[4];

    half8 afrag1 = loadrow_h8(E2 + (size_t)btB[w * 16 + hl] * RANK + kg * 8); // m-rows, E2
    half8 afrag2 = loadrow_h8(E1 + (size_t)btB[w * 16 + hl] * RANK + kg * 8); // m-rows, E1
    float em1v[4];
    #pragma unroll
    for (int q = 0; q < 4; ++q) em1v[q] = emB[w * 16 + kg * 4 + q];

    #pragma unroll
    for (int t = 0; t < 4; ++t) {
        half8 bfrag = loadrow_h8(E1 + (size_t)btA[t * 16 + hl] * RANK + kg * 8); // k-rows
        f32x4 acc = {0.f, 0.f, 0.f, 0.f};
        acc = __builtin_amdgcn_mfma_f32_16x16x32_f16(afrag1, bfrag, acc, 0, 0, 0);
        half4 hv;
        #pragma unroll
        for (int q = 0; q < 4; ++q) hv[q] = (_Float16)exp2f((acc[q] + em1v[q]) * LOG2E);
        *(half4*)&T1t[t * 16 + hl][w * 16 + kg * 4] = hv;   // [k][m]
    }
    #pragma unroll
    for (int t = 0; t < 4; ++t) {
        half8 bfrag = loadrow_h8(E2 + (size_t)btC[t * 16 + hl] * RANK + kg * 8); // l-rows
        float em2 = emC[t * 16 + hl];
        f32x4 acc = {0.f, 0.f, 0.f, 0.f};
        acc = __builtin_amdgcn_mfma_f32_16x16x32_f16(afrag2, bfrag, acc, 0, 0, 0);
        half4 hv;
        #pragma unroll
        for (int q = 0; q < 4; ++q) hv[q] = (_Float16)exp2f((acc[q] + em2) * LOG2E);
        *(half4*)&T2r[t * 16 + hl][w * 16 + kg * 4] = hv;   // [l][m]
    }
    __syncthreads();

    // Phase C: P[l][k] = sum_m T1t[k][m]*T2r[l][m], K=64 via 2 MFMA.
    const int ra = w * 16 + hl;
    half8 a0 = *(const half8*)&T1t[ra][kg * 8];
    half8 a1 = *(const half8*)&T1t[ra][32 + kg * 8];
    f32x4 pacc[4];
    float mp = -1e30f;
    #pragma unroll
    for (int t = 0; t < 4; ++t) {
        half8 c0 = *(const half8*)&T2r[t * 16 + hl][kg * 8];
        half8 c1 = *(const half8*)&T2r[t * 16 + hl][32 + kg * 8];
        f32x4 acc = {0.f, 0.f, 0.f, 0.f};
        acc = __builtin_amdgcn_mfma_f32_16x16x32_f16(a0, c0, acc, 0, 0, 0);
        acc = __builtin_amdgcn_mfma_f32_16x16x32_f16(a1, c1, acc, 0, 0, 0);
        pacc[t] = acc;
        #pragma unroll
        for (int q = 0; q < 4; ++q) mp = fmaxf(mp, acc[q]);
    }

    #pragma unroll
    for (int off = 32; off > 0; off >>= 1) mp = fmaxf(mp, __shfl_xor(mp, off, 64));
    if (lane == 0) smax[w] = mp;
    __syncthreads();
    float mx = fmaxf(fmaxf(smax[0], smax[1]), fmaxf(smax[2], smax[3]));
    float e  = ceilf(__log2f(mx));
    float c  = exp2f(-e);
    if (tid == 0) scl[(size_t)b * NPAIR + i] = e;

    #pragma unroll
    for (int t = 0; t < 4; ++t) {
        half4 hv;
        #pragma unroll
        for (int q = 0; q < 4; ++q) hv[q] = (_Float16)(pacc[t][q] * c);
        *(half4*)(out + (size_t)(t * 16 + hl) * BEAM + w * 16 + kg * 4) = hv;
    }
}

// ---------------- generic fold: Pout_j = Pin_{2j+1} . Pin_{2j} ---------------
// Same phase-C structure as pair_kernel (verified layout). Inputs row-major
// [to][from] f16 with power-of-2 scale exponents; output likewise, exponent
// = e_in0 + e_in1 + e_new.
template<int NIN>
__global__ __launch_bounds__(256) void fold_kernel(
    const unsigned short* __restrict__ Pin, const float* __restrict__ sin_,
    unsigned short* __restrict__ Pout, float* __restrict__ sout)
{
    constexpr int NOUT = NIN / 2;
    const int blk = blockIdx.x;
    const int b = blk / NOUT, j = blk % NOUT;
    const int tid  = threadIdx.x;
    const int w    = tid >> 6;
    const int lane = tid & 63;
    const int hl   = lane & 15;
    const int kg   = lane >> 4;

    __shared__ _Float16 At[64][72];   // At[k][m] = A[m][k], A = Pin[2j] (applied first)
    __shared__ _Float16 Br[64][72];   // Br[l][m] = B[l][m], B = Pin[2j+1]
    __shared__ float smax[4];

    const unsigned short* A = Pin + ((size_t)(b * NIN + 2 * j)) * (BEAM * BEAM);
    const unsigned short* B = A + BEAM * BEAM;

    {   // straight copy of B, transposed copy of A (16 halves per thread each)
        int r = tid >> 2, c = (tid & 3) * 16;
        half8 vb0 = *(const half8*)(B + r * BEAM + c);
        half8 vb1 = *(const half8*)(B + r * BEAM + c + 8);
        *(half8*)&Br[r][c]     = vb0;
        *(half8*)&Br[r][c + 8] = vb1;
        half8 va0 = *(const half8*)(A + r * BEAM + c);
        half8 va1 = *(const half8*)(A + r * BEAM + c + 8);
        #pragma unroll
        for (int q = 0; q < 8; ++q) At[c + q][r]     = va0[q];
        #pragma unroll
        for (int q = 0; q < 8; ++q) At[c + 8 + q][r] = va1[q];
    }
    __syncthreads();

    const int ra = w * 16 + hl;
    half8 a0 = *(const half8*)&At[ra][kg * 8];
    half8 a1 = *(const half8*)&At[ra][32 + kg * 8];
    f32x4 pacc[4];
    float mp = -1e30f;
    #pragma unroll
    for (int t = 0; t < 4; ++t) {
        half8 c0 = *(const half8*)&Br[t * 16 + hl][kg * 8];
        half8 c1 = *(const half8*)&Br[t * 16 + hl][32 + kg * 8];
        f32x4 acc = {0.f, 0.f, 0.f, 0.f};
        acc = __builtin_amdgcn_mfma_f32_16x16x32_f16(a0, c0, acc, 0, 0, 0);
        acc = __builtin_amdgcn_mfma_f32_16x16x32_f16(a1, c1, acc, 0, 0, 0);
        pacc[t] = acc;
        #pragma unroll
        for (int q = 0; q < 4; ++q) mp = fmaxf(mp, acc[q]);
    }

    #pragma unroll
    for (int off = 32; off > 0; off >>= 1) mp = fmaxf(mp, __shfl_xor(mp, off, 64));
    if (lane == 0) smax[w] = mp;
    __syncthreads();
    float mx = fmaxf(fmaxf(smax[0], smax[1]), fmaxf(smax[2], smax[3]));
    float e  = ceilf(__log2f(mx));
    float c  = exp2f(-e);
    if (tid == 0)
        sout[(size_t)b * NOUT + j] = sin_[(size_t)b * NIN + 2 * j]
                                   + sin_[(size_t)b * NIN + 2 * j + 1] + e;

    unsigned short* out = Pout + ((size_t)(b * NOUT + j)) * (BEAM * BEAM);
    #pragma unroll
    for (int t = 0; t < 4; ++t) {
        half4 hv;
        #pragma unroll
        for (int q = 0; q < 4; ++q) hv[q] = (_Float16)(pacc[t][q] * c);
        *(half4*)(out + (size_t)(t * 16 + hl) * BEAM + w * 16 + kg * 4) = hv;
    }
}

// ---------------- sequential beam recursion, 1 wave per batch ----------------
// NOCT=64 steps (octo-folded). v' = O v; renorm by v0; scale exponents re-added
// to M off the critical chain.
__global__ __launch_bounds__(64) void recur_kernel(
    const unsigned short* __restrict__ Obuf, const float* __restrict__ beam_em,
    const float* __restrict__ scl, float* __restrict__ denom)
{
    int b = blockIdx.x, l = threadIdx.x;
    const float* bem = beam_em + (size_t)b * SS * BEAM;
    const float* scb = scl + (size_t)b * NOCT;
    float sc = bem[l] * LOG2E;
    float M = rfl(sc);
    float v = exp2f(sc - M);   // lane l holds v_l, lane0-normalized

    const uint4* Trow = (const uint4*)(Obuf + (size_t)b * NOCT * (BEAM * BEAM)) + (size_t)l * 8;

    uint4 b0[8], b1[8], b2[8], b3[8];
    float l0, l1, l2, l3;

#define LOADT(BUF, STP) do { \
    const uint4* _p = Trow + (size_t)(STP) * 512; \
    _Pragma("unroll") \
    for (int i = 0; i < 8; ++i) BUF[i] = _p[i]; \
} while (0)

    LOADT(b0, 0); LOADT(b1, 1); LOADT(b2, 2); LOADT(b3, 3);
    l0 = scb[0]; l1 = scb[1]; l2 = scb[2]; l3 = scb[3];

#define STEP(BUF, LC) do { \
    float vn = dpp_xor1(v); \
    half2v ph; ph.x = (_Float16)v; ph.y = (_Float16)vn; \
    float pf = __builtin_bit_cast(float, ph); /* even lanes: (v_l, v_{l+1}) */ \
    float a[8]; \
    _Pragma("unroll") \
    for (int i = 0; i < 8; ++i) { \
        uint4 t = BUF[i]; \
        float ai = fdot2f(rl(pf, 8 * i + 0), __builtin_bit_cast(float, t.x), 0.f); \
        ai = fdot2f(rl(pf, 8 * i + 2), __builtin_bit_cast(float, t.y), ai); \
        ai = fdot2f(rl(pf, 8 * i + 4), __builtin_bit_cast(float, t.z), ai); \
        ai = fdot2f(rl(pf, 8 * i + 6), __builtin_bit_cast(float, t.w), ai); \
        a[i] = ai; \
    } \
    float s = ((a[0] + a[1]) + (a[2] + a[3])) + ((a[4] + a[5]) + (a[6] + a[7])); \
    float v0 = rfl(s); \
    M += __log2f(v0) + (LC);           /* off the v-chain; restores 2^-e scale */ \
    v = s * __builtin_amdgcn_rcpf(v0); \
} while (0)

    for (int t = 0; t < 60; t += 4) {
        STEP(b0, l0); LOADT(b0, t + 4); l0 = scb[t + 4];
        STEP(b1, l1); LOADT(b1, t + 5); l1 = scb[t + 5];
        STEP(b2, l2); LOADT(b2, t + 6); l2 = scb[t + 6];
        STEP(b3, l3); LOADT(b3, t + 7); l3 = scb[t + 7];
    }
    // steps 60..63
    STEP(b0, l0);
    STEP(b1, l1);
    STEP(b2, l2);
    STEP(b3, l3);

    float s = wavesum(v);
    if (l == 0) denom[b] = (__log2f(s) + M) * LN2;
#undef STEP
#undef LOADT
}

// ---------------- finalize ----------------
__global__ __launch_bounds__(64) void fin_kernel(
    const float* __restrict__ numer, const float* __restrict__ denom,
    float* __restrict__ out)
{
    int tid = threadIdx.x;
    float llh = 0.f;
    if (tid < BB) {
        llh = numer[tid] - denom[tid];
        out[1 + tid] = llh;
    }
    float s = llh;
    #pragma unroll
    for (int off = 4; off > 0; off >>= 1) s += __shfl_xor(s, off, 64);
    if (tid == 0) out[0] = s;
}

extern "C" void kernel_launch(void* const* d_in, const int* in_sizes, int n_in,
                              void* d_out, int out_size, void* d_ws, size_t ws_size,
                              hipStream_t stream) {
    const float* emissions = (const float*)d_in[0];
    const int*   targets   = (const int*)d_in[1];
    const float* E1        = (const float*)d_in[3];
    const float* E2        = (const float*)d_in[4];
    float* out = (float*)d_out;

    char* w = (char*)d_ws;
    float* numer = (float*)w;                                   // 32 B
    float* denom = (float*)(w + 256);                           // 32 B
    float* sclP  = (float*)(w + 4096);                          // 8 KB
    float* sclQ  = (float*)(w + 16384);                         // 4 KB
    float* sclO  = (float*)(w + 24576);                         // 2 KB
    int*   btgt  = (int*)(w + 65536);                           // 1 MiB
    float* bem   = (float*)(w + 65536 + (1u << 20));            // 1 MiB
    unsigned short* Pbuf = (unsigned short*)(w + 65536 + (2u  << 20)); // 16 MiB
    unsigned short* Qbuf = (unsigned short*)(w + 65536 + (18u << 20)); //  8 MiB
    unsigned short* Obuf = (unsigned short*)(w + 65536 + (26u << 20)); //  4 MiB

    num_kernel        <<<BB, 256, 0, stream>>>(emissions, targets, E1, E2, numer);
    topk_kernel       <<<BB * SS, 256, 0, stream>>>(emissions, targets, btgt, bem);
    pair_kernel       <<<BB * NPAIR, 256, 0, stream>>>(E1, E2, btgt, bem, Pbuf, sclP);
    fold_kernel<NPAIR><<<BB * NQUAD, 256, 0, stream>>>(Pbuf, sclP, Qbuf, sclQ);
    fold_kernel<NQUAD><<<BB * NOCT,  256, 0, stream>>>(Qbuf, sclQ, Obuf, sclO);
    recur_kernel      <<<BB, 64, 0, stream>>>(Obuf, bem, sclO, denom);
    fin_kernel        <<<1, 64, 0, stream>>>(numer, denom, out);
}